// Round 1
// baseline (660.228 us; speedup 1.0000x reference)
//
#include <hip/hip_runtime.h>

// VectorQuantizer: z (32,64,64,64) fp32, codebook (1024,64) fp32.
// out = [z_q_st flat (8388608), vq_loss (1)]  (fp32)
// z_q_st == codebook[argmin_j ||z_vec - e_j||^2] scattered back to NCHW.
// vq_loss == 1.25 * mean((z_q - z)^2).

constexpr int DIM    = 64;
constexpr int NCODES = 1024;
constexpr int HWSZ   = 4096;     // 64*64
constexpr int NPOS   = 131072;   // 32*4096
constexpr int TILE   = 256;      // codes per LDS tile (64 KB)
constexpr int PPT    = 2;        // positions per thread
constexpr int BLOCK  = 256;

__global__ void vq_zero(float* acc) { acc[0] = 0.f; }

__global__ __launch_bounds__(BLOCK) void vq_norms(const float* __restrict__ cb,
                                                  float* __restrict__ norms) {
    int j = blockIdx.x * BLOCK + threadIdx.x;
    if (j < NCODES) {
        const float4* row = (const float4*)(cb + j * DIM);
        float s = 0.f;
#pragma unroll
        for (int i = 0; i < DIM / 4; i++) {
            float4 v = row[i];
            s += v.x * v.x + v.y * v.y + v.z * v.z + v.w * v.w;
        }
        norms[j] = s;
    }
}

__global__ __launch_bounds__(BLOCK) void vq_main(const float* __restrict__ z,
                                                 const float* __restrict__ cb,
                                                 const float* __restrict__ norms,
                                                 float* __restrict__ out,
                                                 float* __restrict__ loss_acc) {
    __shared__ float lds_cb[TILE * DIM];   // 64 KB
    __shared__ float lds_n[TILE];
    __shared__ float wsum[BLOCK / 64];

    const int tid = threadIdx.x;
    const int pbase = blockIdx.x * (BLOCK * PPT) + tid;

    // Load this thread's z vectors (coalesced across lanes for each c).
    float zv[PPT][DIM];
#pragma unroll
    for (int p = 0; p < PPT; p++) {
        int n = pbase + p * BLOCK;
        int b = n >> 12;
        int hw = n & 4095;
        const float* zp = z + (size_t)b * (DIM * HWSZ) + hw;
#pragma unroll
        for (int c = 0; c < DIM; c++) zv[p][c] = zp[c * HWSZ];
    }

    float best[PPT];
    int bestj[PPT];
#pragma unroll
    for (int p = 0; p < PPT; p++) { best[p] = 3.4e38f; bestj[p] = 0; }

    for (int t = 0; t < NCODES / TILE; t++) {
        __syncthreads();
        // Stage codebook tile into LDS (coalesced float4).
        const float4* src = (const float4*)(cb + (size_t)t * TILE * DIM);
        float4* dst = (float4*)lds_cb;
#pragma unroll
        for (int i = 0; i < TILE * DIM / 4 / BLOCK; i++)
            dst[tid + i * BLOCK] = src[tid + i * BLOCK];
        lds_n[tid] = norms[t * TILE + tid];   // TILE == BLOCK
        __syncthreads();

        for (int jj = 0; jj < TILE; jj++) {
            const float4* row = (const float4*)(lds_cb + jj * DIM);
            float dot[PPT];
#pragma unroll
            for (int p = 0; p < PPT; p++) dot[p] = 0.f;
#pragma unroll
            for (int d4 = 0; d4 < DIM / 4; d4++) {
                float4 e4 = row[d4];   // broadcast read (all lanes same addr)
#pragma unroll
                for (int p = 0; p < PPT; p++) {
                    dot[p] += zv[p][d4 * 4 + 0] * e4.x + zv[p][d4 * 4 + 1] * e4.y
                            + zv[p][d4 * 4 + 2] * e4.z + zv[p][d4 * 4 + 3] * e4.w;
                }
            }
            float nj = lds_n[jj];
            int j = t * TILE + jj;
#pragma unroll
            for (int p = 0; p < PPT; p++) {
                float score = nj - 2.f * dot[p];   // |z|^2 omitted: argmin-invariant
                if (score < best[p]) { best[p] = score; bestj[p] = j; }  // strict <: first-min
            }
        }
    }

    // Epilogue: write z_q (NCHW scatter, coalesced across lanes per c) + loss partial.
    float lsum = 0.f;
#pragma unroll
    for (int p = 0; p < PPT; p++) {
        int n = pbase + p * BLOCK;
        int b = n >> 12;
        int hw = n & 4095;
        float* op = out + (size_t)b * (DIM * HWSZ) + hw;
        const float4* e4p = (const float4*)(cb + (size_t)bestj[p] * DIM);
#pragma unroll
        for (int d4 = 0; d4 < DIM / 4; d4++) {
            float4 q = e4p[d4];
            float d0 = q.x - zv[p][d4 * 4 + 0];
            float d1 = q.y - zv[p][d4 * 4 + 1];
            float d2 = q.z - zv[p][d4 * 4 + 2];
            float d3 = q.w - zv[p][d4 * 4 + 3];
            lsum += d0 * d0 + d1 * d1 + d2 * d2 + d3 * d3;
            op[(d4 * 4 + 0) * HWSZ] = q.x;
            op[(d4 * 4 + 1) * HWSZ] = q.y;
            op[(d4 * 4 + 2) * HWSZ] = q.z;
            op[(d4 * 4 + 3) * HWSZ] = q.w;
        }
    }

    // Wave reduce (64 lanes) then block reduce then one atomic per block.
#pragma unroll
    for (int off = 32; off > 0; off >>= 1)
        lsum += __shfl_down(lsum, off, 64);
    if ((tid & 63) == 0) wsum[tid >> 6] = lsum;
    __syncthreads();
    if (tid == 0) {
        float s = 0.f;
#pragma unroll
        for (int w = 0; w < BLOCK / 64; w++) s += wsum[w];
        atomicAdd(loss_acc, s);
    }
}

__global__ void vq_finalize(const float* __restrict__ loss_acc,
                            float* __restrict__ out_loss) {
    out_loss[0] = 1.25f * loss_acc[0] / (float)((size_t)NPOS * DIM);
}

extern "C" void kernel_launch(void* const* d_in, const int* in_sizes, int n_in,
                              void* d_out, int out_size, void* d_ws, size_t ws_size,
                              hipStream_t stream) {
    const float* z  = (const float*)d_in[0];
    const float* cb = (const float*)d_in[1];
    float* out = (float*)d_out;

    float* loss_acc = (float*)d_ws;            // 1 float
    float* norms    = (float*)d_ws + 64;       // 1024 floats

    vq_zero<<<1, 1, 0, stream>>>(loss_acc);
    vq_norms<<<NCODES / BLOCK, BLOCK, 0, stream>>>(cb, norms);
    vq_main<<<NPOS / (BLOCK * PPT), BLOCK, 0, stream>>>(z, cb, norms, out, loss_acc);
    vq_finalize<<<1, 1, 0, stream>>>(loss_acc, out + (size_t)NPOS * DIM);
}

// Round 2
// 133.471 us; speedup vs baseline: 4.9466x; 4.9466x over previous
//
#include <hip/hip_runtime.h>

// VectorQuantizer: z (32,64,64,64) fp32, codebook (1024,64) fp32.
// out = [z_q_st flat (8388608), vq_loss (1)]  (fp32)
// R2: fused bf16-MFMA GEMM (scores = |e|^2 - 2 z.e) + per-row argmin.
// loss_p = |z_p|^2 + best_score_p  (exact |z|^2 in fp32, so no 2nd z pass).

constexpr int DIM    = 64;
constexpr int NCODES = 1024;
constexpr int HWSZ   = 4096;     // 64*64
constexpr int NPOS   = 131072;   // 32*4096
constexpr int BLOCK  = 256;      // 4 waves; each wave: 4 n-tiles of 16 rows
constexpr int JT     = 512;      // codes staged per LDS pass (64 KB)

typedef __bf16 bf16x8 __attribute__((ext_vector_type(8)));
typedef unsigned short ushort8t __attribute__((ext_vector_type(8)));
typedef float f32x4 __attribute__((ext_vector_type(4)));

__device__ __forceinline__ unsigned short f2bf(float f) {
    unsigned u = __float_as_uint(f);
    u += 0x7fffu + ((u >> 16) & 1u);   // RTNE
    return (unsigned short)(u >> 16);
}

// norms[j] = |e_j|^2 (fp32 exact); block 0 also zeroes the loss accumulator.
__global__ __launch_bounds__(BLOCK) void vq_norms(const float* __restrict__ cb,
                                                  float* __restrict__ norms,
                                                  float* __restrict__ loss_acc) {
    int j = blockIdx.x * BLOCK + threadIdx.x;
    if (j == 0) loss_acc[0] = 0.f;
    if (j < NCODES) {
        const float4* row = (const float4*)(cb + (size_t)j * DIM);
        float s = 0.f;
#pragma unroll
        for (int i = 0; i < DIM / 4; i++) {
            float4 v = row[i];
            s += v.x * v.x + v.y * v.y + v.z * v.z + v.w * v.w;
        }
        norms[j] = s;
    }
}

__global__ __launch_bounds__(BLOCK, 2) void vq_main(const float* __restrict__ z,
                                                    const float* __restrict__ cb,
                                                    const float* __restrict__ norms,
                                                    float* __restrict__ out,
                                                    float* __restrict__ loss_acc) {
    // 64 KB codebook tile (bf16, 16B-groups XOR-swizzled by row&7 -> <=2-way conflicts)
    __shared__ __align__(16) unsigned short cb_lds[JT * DIM];
    __shared__ float n_lds[NCODES];       // 4 KB
    __shared__ int   bj_lds[BLOCK];       // 1 KB
    __shared__ float ls_lds[BLOCK / 64];

    const int tid  = threadIdx.x;
    const int w    = tid >> 6;        // wave 0..3
    const int lane = tid & 63;
    const int q    = lane >> 4;       // quad 0..3
    const int r    = lane & 15;       // A row (m) / B col (j-within-tile) / C col
    const int p0   = blockIdx.x * BLOCK;
    const int b    = p0 >> 12;
    const int hwb  = p0 & 4095;

    for (int i = tid; i < NCODES; i += BLOCK) n_lds[i] = norms[i];

    // ---- Load A fragments for this wave's 4 n-tiles (z touched exactly once) ----
    // A layout (16x16x32): lane holds A[m=lane&15][k = q*8 + i] per K-half.
    bf16x8 afrag[4][2];
    float  zsq[4];
    const float* zb = z + (size_t)b * DIM * HWSZ + hwb + w * 64 + r;
#pragma unroll
    for (int t = 0; t < 4; t++) {
        float sq = 0.f;
#pragma unroll
        for (int h = 0; h < 2; h++) {
            ushort8t u;
#pragma unroll
            for (int i = 0; i < 8; i++) {
                float v = zb[(size_t)(h * 32 + q * 8 + i) * HWSZ + t * 16];
                sq += v * v;
                u[i] = f2bf(v);
            }
            afrag[t][h] = __builtin_bit_cast(bf16x8, u);
        }
        // full |z_p|^2 for row r: sum the 4 quads' partials
        sq += __shfl_xor(sq, 16, 64);
        sq += __shfl_xor(sq, 32, 64);
        zsq[t] = sq;
    }

    float best[4][4];
    int   bestj[4][4];
#pragma unroll
    for (int t = 0; t < 4; t++)
#pragma unroll
        for (int g = 0; g < 4; g++) { best[t][g] = 3.4e38f; bestj[t][g] = 0; }

    for (int pass = 0; pass < 2; pass++) {
        __syncthreads();
        // ---- Stage 512 codes -> bf16 LDS, swizzled ----
        const float4* src = (const float4*)(cb + (size_t)pass * JT * DIM);
#pragma unroll
        for (int it = 0; it < (JT * 8) / BLOCK; it++) {
            int m = tid + it * BLOCK;
            int j = m >> 3, g = m & 7;          // row j, 8-elem group g
            float4 v0 = src[j * 16 + g * 2];
            float4 v1 = src[j * 16 + g * 2 + 1];
            ushort8t u;
            u[0] = f2bf(v0.x); u[1] = f2bf(v0.y); u[2] = f2bf(v0.z); u[3] = f2bf(v0.w);
            u[4] = f2bf(v1.x); u[5] = f2bf(v1.y); u[6] = f2bf(v1.z); u[7] = f2bf(v1.w);
            int gs = g ^ (j & 7);
            *(ushort8t*)&cb_lds[(j * 8 + gs) * 8] = u;
        }
        __syncthreads();

        // ---- Sweep 32 j-tiles of 16 codes ----
        for (int jt = 0; jt < JT / 16; jt++) {
            // B layout: lane holds B[k=q*8+i][n'=lane&15]; B[k][n'] = cb[jbase+n'][k]
            bf16x8 bfrag[2];
#pragma unroll
            for (int h = 0; h < 2; h++) {
                int grp = (h * 4 + q) ^ ((jt * 16 + r) & 7);
                bfrag[h] = *(const bf16x8*)&cb_lds[(jt * 16 + r) * 64 + grp * 8];
            }
            float nj    = n_lds[pass * JT + jt * 16 + r];
            int   jglob = pass * JT + jt * 16 + r;
#pragma unroll
            for (int t = 0; t < 4; t++) {
                f32x4 acc = {0.f, 0.f, 0.f, 0.f};
                acc = __builtin_amdgcn_mfma_f32_16x16x32_bf16(afrag[t][0], bfrag[0], acc, 0, 0, 0);
                acc = __builtin_amdgcn_mfma_f32_16x16x32_bf16(afrag[t][1], bfrag[1], acc, 0, 0, 0);
                // C/D: col = lane&15 (j), row = q*4 + g (n within tile)
#pragma unroll
                for (int g = 0; g < 4; g++) {
                    float s = fmaf(-2.f, acc[g], nj);
                    if (s < best[t][g]) { best[t][g] = s; bestj[t][g] = jglob; }
                }
            }
        }
    }

    // ---- Cross-column argmin: reduce over the 16 j-lanes of each quad ----
#pragma unroll
    for (int t = 0; t < 4; t++)
#pragma unroll
        for (int g = 0; g < 4; g++) {
            float s = best[t][g]; int j = bestj[t][g];
#pragma unroll
            for (int off = 1; off < 16; off <<= 1) {
                float s2 = __shfl_xor(s, off, 64);
                int   j2 = __shfl_xor(j, off, 64);
                if (s2 < s || (s2 == s && j2 < j)) { s = s2; j = j2; }
            }
            best[t][g] = s; bestj[t][g] = j;
        }

    // Writer lanes: lane where q == r>>2 holds best for row m == r AND zsq for row r.
    float lsum = 0.f;
    if (q == (r >> 2)) {
        int g = r & 3;
#pragma unroll
        for (int t = 0; t < 4; t++) {
            bj_lds[w * 64 + t * 16 + r] = bestj[t][g];
            lsum += zsq[t] + best[t][g];     // = |z-e_best|^2 (bf16-dot approx)
        }
    }
#pragma unroll
    for (int off = 32; off > 0; off >>= 1) lsum += __shfl_down(lsum, off, 64);
    if (lane == 0) ls_lds[w] = lsum;
    __syncthreads();
    if (tid == 0) {
        float s = ls_lds[0] + ls_lds[1] + ls_lds[2] + ls_lds[3];
        atomicAdd(loss_acc, s);
    }

    // ---- Epilogue: gather exact fp32 codebook rows, scatter to NCHW (coalesced) ----
    int myj = bj_lds[tid];
    const float* crow = cb + (size_t)myj * DIM;
    float* ob = out + (size_t)b * DIM * HWSZ + hwb + tid;
#pragma unroll
    for (int c = 0; c < DIM; c++) ob[(size_t)c * HWSZ] = crow[c];
}

__global__ void vq_finalize(const float* __restrict__ loss_acc,
                            float* __restrict__ out_loss) {
    out_loss[0] = 1.25f * loss_acc[0] / (float)((size_t)NPOS * DIM);
}

extern "C" void kernel_launch(void* const* d_in, const int* in_sizes, int n_in,
                              void* d_out, int out_size, void* d_ws, size_t ws_size,
                              hipStream_t stream) {
    const float* z  = (const float*)d_in[0];
    const float* cb = (const float*)d_in[1];
    float* out = (float*)d_out;

    float* loss_acc = (float*)d_ws;        // 1 float
    float* norms    = (float*)d_ws + 64;   // 1024 floats

    vq_norms<<<NCODES / BLOCK, BLOCK, 0, stream>>>(cb, norms, loss_acc);
    vq_main<<<NPOS / BLOCK, BLOCK, 0, stream>>>(z, cb, norms, out, loss_acc);
    vq_finalize<<<1, 1, 0, stream>>>(loss_acc, out + (size_t)NPOS * DIM);
}

// Round 3
// 129.587 us; speedup vs baseline: 5.0949x; 1.0300x over previous
//
#include <hip/hip_runtime.h>

// VectorQuantizer: z (32,64,64,64) fp32, codebook (1024,64) fp32.
// out = [z_q_st flat (8388608), vq_loss (1)]  (fp32)
// R3: prep kernel pre-converts codebook -> bf16 (swizzled for global_load_lds),
// MFMA scores with nj folded into acc init (acc = 1 - nj/2 + dot, positive ->
// monotonic fp32 bits), index packed in low 10 mantissa bits, argmin = v_max_u32.
// Loss finalized in-kernel via fence + ticket counter (2 kernels total).

constexpr int DIM    = 64;
constexpr int NCODES = 1024;
constexpr int HWSZ   = 4096;     // 64*64
constexpr int NPOS   = 131072;   // 32*4096
constexpr int BLOCK  = 512;      // 8 waves
constexpr int PPB    = 256;      // positions per block (8 waves x 2 tiles x 16)
constexpr int GRID   = NPOS / PPB;   // 512
constexpr int JT     = 512;      // codes per LDS pass (64 KB bf16)

typedef __bf16 bf16x8 __attribute__((ext_vector_type(8)));
typedef unsigned short ushort8t __attribute__((ext_vector_type(8)));
typedef float f32x4 __attribute__((ext_vector_type(4)));

__device__ __forceinline__ unsigned short f2bf(float f) {
    unsigned u = __float_as_uint(f);
    u += 0x7fffu + ((u >> 16) & 1u);   // RTNE
    return (unsigned short)(u >> 16);
}

// Prep: codebook -> bf16, pre-swizzled (16B group g of row j stored at slot
// g^(j&7)) so a LINEAR global_load_lds copy lands conflict-free in LDS.
// Also: exact fp32 row norms, zero loss accumulator + ticket counter.
__global__ __launch_bounds__(256) void vq_prep(const float* __restrict__ cb,
                                               float* __restrict__ norms,
                                               unsigned short* __restrict__ cbbf,
                                               float* __restrict__ loss_acc,
                                               unsigned* __restrict__ counter) {
    int m = blockIdx.x * 256 + threadIdx.x;   // 0..8191: (row j, group g)
    if (m == 0) { loss_acc[0] = 0.f; counter[0] = 0u; }
    int j = m >> 3, g = m & 7;
    const float4* src = (const float4*)(cb + (size_t)j * DIM + g * 8);
    float4 v0 = src[0], v1 = src[1];
    ushort8t u;
    u[0] = f2bf(v0.x); u[1] = f2bf(v0.y); u[2] = f2bf(v0.z); u[3] = f2bf(v0.w);
    u[4] = f2bf(v1.x); u[5] = f2bf(v1.y); u[6] = f2bf(v1.z); u[7] = f2bf(v1.w);
    float ps = v0.x * v0.x + v0.y * v0.y + v0.z * v0.z + v0.w * v0.w
             + v1.x * v1.x + v1.y * v1.y + v1.z * v1.z + v1.w * v1.w;
    // rows occupy aligned 8-lane groups: reduce within the group
    ps += __shfl_xor(ps, 1, 64);
    ps += __shfl_xor(ps, 2, 64);
    ps += __shfl_xor(ps, 4, 64);
    if (g == 0) norms[j] = ps;
    *(ushort8t*)(cbbf + ((size_t)j * 8 + (g ^ (j & 7))) * 8) = u;
}

__global__ __launch_bounds__(BLOCK, 4) void vq_main(const float* __restrict__ z,
                                                    const float* __restrict__ cb,
                                                    const float* __restrict__ norms,
                                                    const unsigned short* __restrict__ cbbf,
                                                    float* __restrict__ out,
                                                    float* __restrict__ loss_acc,
                                                    unsigned* __restrict__ counter) {
    __shared__ __align__(16) unsigned short cb_lds[JT * DIM];  // 64 KB
    __shared__ __align__(16) float n_lds[NCODES];              // 4 KB
    __shared__ int   bj_lds[PPB];                              // 1 KB
    __shared__ float ls_lds[BLOCK / 64];

    const int tid  = threadIdx.x;
    const int w    = tid >> 6;        // wave 0..7
    const int lane = tid & 63;
    const int q    = lane >> 4;       // quad 0..3
    const int r    = lane & 15;
    const int p0   = blockIdx.x * PPB;
    const int b    = p0 >> 12;
    const int hwb  = p0 & 4095;

    // Stage all 1024 norms (4 KB) via async DMA (waves 0..3, wave-uniform branch).
    if (tid < 256) {
        __builtin_amdgcn_global_load_lds(
            (const __attribute__((address_space(1))) void*)(norms + tid * 4),
            (__attribute__((address_space(3))) void*)(&n_lds[tid * 4]), 16, 0, 0);
    }

    // ---- A fragments: 2 n-tiles per wave. Lane holds A[m=r][k=q*8+i] per half. ----
    bf16x8 afrag[2][2];
    float  zsq[2];
    const float* zb = z + (size_t)b * DIM * HWSZ + hwb + w * 32 + r;
#pragma unroll
    for (int t = 0; t < 2; t++) {
        float sq = 0.f;
#pragma unroll
        for (int h = 0; h < 2; h++) {
            ushort8t u;
#pragma unroll
            for (int i = 0; i < 8; i++) {
                float v = zb[(size_t)(h * 32 + q * 8 + i) * HWSZ + t * 16];
                sq = fmaf(v, v, sq);
                u[i] = f2bf(v);
            }
            afrag[t][h] = __builtin_bit_cast(bf16x8, u);
        }
        sq += __shfl_xor(sq, 16, 64);   // sum quads -> full |z_row|^2
        sq += __shfl_xor(sq, 32, 64);
        zsq[t] = sq;
    }

    unsigned best[2][4];
#pragma unroll
    for (int t = 0; t < 2; t++)
#pragma unroll
        for (int g = 0; g < 4; g++) best[t][g] = 0u;   // packed floats are >0

    for (int pass = 0; pass < 2; pass++) {
        __syncthreads();
        // Linear async copy of 64 KB pre-swizzled bf16 codebook tile.
        const char* gsrc = (const char*)cbbf + (size_t)pass * (JT * DIM * 2);
#pragma unroll
        for (int it = 0; it < (JT * DIM * 2) / (BLOCK * 16); it++) {
            int off = (it * BLOCK + tid) * 16;
            __builtin_amdgcn_global_load_lds(
                (const __attribute__((address_space(1))) void*)(gsrc + off),
                (__attribute__((address_space(3))) void*)((char*)cb_lds + off), 16, 0, 0);
        }
        __syncthreads();

        for (int jt = 0; jt < JT / 16; jt++) {
            const int row = jt * 16 + r;          // code row within tile
            // B layout: lane holds B[k=h*32+q*8+i][n'=r] = e_row[k]; groups swizzled.
            bf16x8 bfrag[2];
#pragma unroll
            for (int h = 0; h < 2; h++) {
                int grp = (h * 4 + q) ^ (row & 7);
                bfrag[h] = *(const bf16x8*)&cb_lds[(size_t)row * 64 + grp * 8];
            }
            float nj = n_lds[pass * JT + row];
            float cinit = fmaf(-0.5f, nj, 1.0f);          // acc = 1 - nj/2 + dot > 0
            unsigned inv_j = (unsigned)(1023 - (pass * JT + row));
#pragma unroll
            for (int t = 0; t < 2; t++) {
                f32x4 acc = {cinit, cinit, cinit, cinit};
                acc = __builtin_amdgcn_mfma_f32_16x16x32_bf16(afrag[t][0], bfrag[0], acc, 0, 0, 0);
                acc = __builtin_amdgcn_mfma_f32_16x16x32_bf16(afrag[t][1], bfrag[1], acc, 0, 0, 0);
#pragma unroll
                for (int g = 0; g < 4; g++) {
                    // pack index into low 10 mantissa bits; max == min-dist, ties -> low j
                    unsigned bits = (__float_as_uint(acc[g]) & ~1023u) | inv_j;
                    best[t][g] = best[t][g] > bits ? best[t][g] : bits;
                }
            }
        }
    }

    // ---- Column-argmax reduce over the 16 j-lanes of each quad ----
#pragma unroll
    for (int t = 0; t < 2; t++)
#pragma unroll
        for (int g = 0; g < 4; g++) {
            unsigned v = best[t][g];
#pragma unroll
            for (int off = 1; off < 16; off <<= 1) {
                unsigned v2 = __shfl_xor((int)v, off, 64);
                v = v > v2 ? v : v2;
            }
            best[t][g] = v;
        }

    // Writer lane for row m=r: quad q == r>>2 holds best for g == r&3; zsq[t] is per-r.
    float lsum = 0.f;
    if (q == (r >> 2)) {
        int g = r & 3;
#pragma unroll
        for (int t = 0; t < 2; t++) {
            unsigned v = best[t][0];
            v = (g == 1) ? best[t][1] : v;
            v = (g == 2) ? best[t][2] : v;
            v = (g == 3) ? best[t][3] : v;
            bj_lds[w * 32 + t * 16 + r] = 1023 - (int)(v & 1023u);
            // dist = |z|^2 + nj - 2*dot = zsq + 2 - 2*acc  (acc low bits ~ index, err<=1.2e-4)
            lsum += zsq[t] + 2.f - 2.f * __uint_as_float(v);
        }
    }
#pragma unroll
    for (int off = 32; off > 0; off >>= 1) lsum += __shfl_down(lsum, off, 64);
    if (lane == 0) ls_lds[w] = lsum;
    __syncthreads();
    if (tid == 0) {
        float s = 0.f;
#pragma unroll
        for (int i = 0; i < BLOCK / 64; i++) s += ls_lds[i];
        atomicAdd(loss_acc, s);
        __threadfence();
        unsigned old = atomicAdd(counter, 1u);
        if (old == GRID - 1) {
            float total = atomicAdd(loss_acc, 0.f);   // RMW read: device-coherent
            out[(size_t)NPOS * DIM] = 1.25f * total / (float)((size_t)NPOS * DIM);
        }
    }

    // ---- Epilogue: gather exact fp32 rows, scatter NCHW. 2 threads per position. ----
    int posi = tid >> 1;        // 0..255
    int half = tid & 1;
    int myj  = bj_lds[posi];
    const float* crow = cb + (size_t)myj * DIM + half * 32;
    float* ob = out + (size_t)b * DIM * HWSZ + (size_t)(half * 32) * HWSZ + hwb + posi;
#pragma unroll
    for (int c = 0; c < 32; c++) ob[(size_t)c * HWSZ] = crow[c];
}

extern "C" void kernel_launch(void* const* d_in, const int* in_sizes, int n_in,
                              void* d_out, int out_size, void* d_ws, size_t ws_size,
                              hipStream_t stream) {
    const float* z  = (const float*)d_in[0];
    const float* cb = (const float*)d_in[1];
    float* out = (float*)d_out;

    float*          loss_acc = (float*)d_ws;                    // @0
    unsigned*       counter  = (unsigned*)((char*)d_ws + 4);    // @4
    float*          norms    = (float*)((char*)d_ws + 256);     // 4 KB
    unsigned short* cbbf     = (unsigned short*)((char*)d_ws + 4608);  // 128 KB

    vq_prep<<<NCODES * 8 / 256, 256, 0, stream>>>(cb, norms, cbbf, loss_acc, counter);
    vq_main<<<GRID, BLOCK, 0, stream>>>(z, cb, norms, cbbf, out, loss_acc, counter);
}

// Round 4
// 120.900 us; speedup vs baseline: 5.4609x; 1.0719x over previous
//
#include <hip/hip_runtime.h>

// VectorQuantizer: z (32,64,64,64) fp32, codebook (1024,64) fp32.
// out = [z_q_st flat (8388608), vq_loss (1)]  (fp32)
// R4: FULL bf16 codebook resident in LDS (128 KB of the 160 KB), 1024-thread
// blocks (16 waves) = 1 block/CU, barrier-free steady state (2 barriers total
// per block vs 4 in R3). Scores via MFMA with nj folded into acc init
// (acc = 1 - nj/2 + dot > 0 -> monotonic fp32 bits), index packed in low 10
// mantissa bits, argmin = v_max_u32. Epilogue: 64-consecutive-position
// stores (256 B/instr, full lines — R2-verified clean WRITE_SIZE).

constexpr int DIM    = 64;
constexpr int NCODES = 1024;
constexpr int HWSZ   = 4096;     // 64*64
constexpr int NPOS   = 131072;   // 32*4096
constexpr int BLOCK  = 1024;     // 16 waves
constexpr int PPB    = 512;      // positions per block (16 waves x 2 tiles x 16)
constexpr int GRID   = NPOS / PPB;   // 256 = 1 block/CU

typedef __bf16 bf16x8 __attribute__((ext_vector_type(8)));
typedef unsigned short ushort8t __attribute__((ext_vector_type(8)));
typedef float f32x4 __attribute__((ext_vector_type(4)));

__device__ __forceinline__ unsigned short f2bf(float f) {
    unsigned u = __float_as_uint(f);
    u += 0x7fffu + ((u >> 16) & 1u);   // RTNE
    return (unsigned short)(u >> 16);
}

// Prep: codebook -> bf16, pre-swizzled (16B group g of row j stored at slot
// g^(j&7)) so a LINEAR global_load_lds copy lands conflict-free in LDS.
// Also: exact fp32 row norms, zero loss accumulator + ticket counter.
__global__ __launch_bounds__(256) void vq_prep(const float* __restrict__ cb,
                                               float* __restrict__ norms,
                                               unsigned short* __restrict__ cbbf,
                                               float* __restrict__ loss_acc,
                                               unsigned* __restrict__ counter) {
    int m = blockIdx.x * 256 + threadIdx.x;   // 0..8191: (row j, group g)
    if (m == 0) { loss_acc[0] = 0.f; counter[0] = 0u; }
    int j = m >> 3, g = m & 7;
    const float4* src = (const float4*)(cb + (size_t)j * DIM + g * 8);
    float4 v0 = src[0], v1 = src[1];
    ushort8t u;
    u[0] = f2bf(v0.x); u[1] = f2bf(v0.y); u[2] = f2bf(v0.z); u[3] = f2bf(v0.w);
    u[4] = f2bf(v1.x); u[5] = f2bf(v1.y); u[6] = f2bf(v1.z); u[7] = f2bf(v1.w);
    float ps = v0.x * v0.x + v0.y * v0.y + v0.z * v0.z + v0.w * v0.w
             + v1.x * v1.x + v1.y * v1.y + v1.z * v1.z + v1.w * v1.w;
    ps += __shfl_xor(ps, 1, 64);
    ps += __shfl_xor(ps, 2, 64);
    ps += __shfl_xor(ps, 4, 64);
    if (g == 0) norms[j] = ps;
    *(ushort8t*)(cbbf + ((size_t)j * 8 + (g ^ (j & 7))) * 8) = u;
}

__global__ __launch_bounds__(BLOCK, 4) void vq_main(const float* __restrict__ z,
                                                    const float* __restrict__ cb,
                                                    const float* __restrict__ norms,
                                                    const unsigned short* __restrict__ cbbf,
                                                    float* __restrict__ out,
                                                    float* __restrict__ loss_acc,
                                                    unsigned* __restrict__ counter) {
    __shared__ __align__(16) unsigned short cb_lds[NCODES * DIM];  // 128 KB
    __shared__ __align__(16) float n_lds[NCODES];                  // 4 KB
    __shared__ int   bj_lds[PPB];                                  // 2 KB
    __shared__ float ls_lds[BLOCK / 64];

    const int tid  = threadIdx.x;
    const int w    = tid >> 6;        // wave 0..15
    const int lane = tid & 63;
    const int q    = lane >> 4;       // quad 0..3
    const int r    = lane & 15;
    const int p0   = blockIdx.x * PPB;
    const int b    = p0 >> 12;
    const int hwb  = p0 & 4095;

    // ---- One-time staging: norms (4 KB) + whole bf16 codebook (128 KB) ----
    if (tid < 256) {
        __builtin_amdgcn_global_load_lds(
            (const __attribute__((address_space(1))) void*)(norms + tid * 4),
            (__attribute__((address_space(3))) void*)(&n_lds[tid * 4]), 16, 0, 0);
    }
#pragma unroll
    for (int it = 0; it < (NCODES * DIM * 2) / (BLOCK * 16); it++) {
        int off = (it * BLOCK + tid) * 16;
        __builtin_amdgcn_global_load_lds(
            (const __attribute__((address_space(1))) void*)((const char*)cbbf + off),
            (__attribute__((address_space(3))) void*)((char*)cb_lds + off), 16, 0, 0);
    }

    // ---- A fragments: 2 n-tiles per wave (overlaps with staging DMA). ----
    // A layout (16x16x32): lane holds A[m=r][k=q*8+i] per K-half.
    bf16x8 afrag[2][2];
    float  zsq[2];
    const float* zb = z + (size_t)b * DIM * HWSZ + hwb + w * 32 + r;
#pragma unroll
    for (int t = 0; t < 2; t++) {
        float sq = 0.f;
#pragma unroll
        for (int h = 0; h < 2; h++) {
            ushort8t u;
#pragma unroll
            for (int i = 0; i < 8; i++) {
                float v = zb[(size_t)(h * 32 + q * 8 + i) * HWSZ + t * 16];
                sq = fmaf(v, v, sq);
                u[i] = f2bf(v);
            }
            afrag[t][h] = __builtin_bit_cast(bf16x8, u);
        }
        sq += __shfl_xor(sq, 16, 64);   // sum quads -> full |z_row|^2
        sq += __shfl_xor(sq, 32, 64);
        zsq[t] = sq;
    }

    unsigned best[2][4];
#pragma unroll
    for (int t = 0; t < 2; t++)
#pragma unroll
        for (int g = 0; g < 4; g++) best[t][g] = 0u;   // packed floats are >0

    __syncthreads();   // staging complete; NO barriers until epilogue handoff

    // ---- Sweep all 64 j-tiles, barrier-free ----
    for (int jt = 0; jt < NCODES / 16; jt++) {
        const int row = jt * 16 + r;          // code row 0..1023
        // B layout: lane holds B[k=h*32+q*8+i][n'=r] = e_row[k]; groups swizzled.
        bf16x8 bfrag[2];
#pragma unroll
        for (int h = 0; h < 2; h++) {
            int grp = (h * 4 + q) ^ (row & 7);
            bfrag[h] = *(const bf16x8*)&cb_lds[(size_t)row * 64 + grp * 8];
        }
        float nj = n_lds[row];
        float cinit = fmaf(-0.5f, nj, 1.0f);          // acc = 1 - nj/2 + dot > 0
        unsigned inv_j = (unsigned)(1023 - row);
#pragma unroll
        for (int t = 0; t < 2; t++) {
            f32x4 acc = {cinit, cinit, cinit, cinit};
            acc = __builtin_amdgcn_mfma_f32_16x16x32_bf16(afrag[t][0], bfrag[0], acc, 0, 0, 0);
            acc = __builtin_amdgcn_mfma_f32_16x16x32_bf16(afrag[t][1], bfrag[1], acc, 0, 0, 0);
#pragma unroll
            for (int g = 0; g < 4; g++) {
                // pack index into low 10 mantissa bits; max == min-dist, ties -> low j
                unsigned bits = (__float_as_uint(acc[g]) & ~1023u) | inv_j;
                best[t][g] = best[t][g] > bits ? best[t][g] : bits;
            }
        }
    }

    // ---- Column-argmax reduce over the 16 j-lanes of each quad ----
#pragma unroll
    for (int t = 0; t < 2; t++)
#pragma unroll
        for (int g = 0; g < 4; g++) {
            unsigned v = best[t][g];
#pragma unroll
            for (int off = 1; off < 16; off <<= 1) {
                unsigned v2 = __shfl_xor((int)v, off, 64);
                v = v > v2 ? v : v2;
            }
            best[t][g] = v;
        }

    // Writer lane for row m=r: quad q == r>>2 holds best for g == r&3.
    float lsum = 0.f;
    if (q == (r >> 2)) {
        int g = r & 3;
#pragma unroll
        for (int t = 0; t < 2; t++) {
            unsigned v = best[t][0];
            v = (g == 1) ? best[t][1] : v;
            v = (g == 2) ? best[t][2] : v;
            v = (g == 3) ? best[t][3] : v;
            bj_lds[w * 32 + t * 16 + r] = 1023 - (int)(v & 1023u);
            // dist = |z|^2 + nj - 2*dot = zsq + 2 - 2*acc  (low-bit err <= 2.4e-4)
            lsum += zsq[t] + 2.f - 2.f * __uint_as_float(v);
        }
    }
#pragma unroll
    for (int off = 32; off > 0; off >>= 1) lsum += __shfl_down(lsum, off, 64);
    if (lane == 0) ls_lds[w] = lsum;
    __syncthreads();
    if (tid == 0) {
        float s = 0.f;
#pragma unroll
        for (int i = 0; i < BLOCK / 64; i++) s += ls_lds[i];
        atomicAdd(loss_acc, s);
        __threadfence();
        unsigned old = atomicAdd(counter, 1u);
        if (old == GRID - 1) {
            float total = atomicAdd(loss_acc, 0.f);   // RMW read: device-coherent
            out[(size_t)NPOS * DIM] = 1.25f * total / (float)((size_t)NPOS * DIM);
        }
    }

    // ---- Epilogue: half-row per thread; 64 consecutive positions per store
    // instr (256 B, full cache lines — the R2-verified clean pattern). ----
    int half = tid >> 9;        // 0/1: c-halves
    int posi = tid & 511;       // 512 positions
    int myj  = bj_lds[posi];
    const float* crow = cb + (size_t)myj * DIM + half * 32;
    float* ob = out + (size_t)b * DIM * HWSZ + (size_t)(half * 32) * HWSZ + hwb + posi;
#pragma unroll
    for (int c = 0; c < 32; c++) ob[(size_t)c * HWSZ] = crow[c];
}

extern "C" void kernel_launch(void* const* d_in, const int* in_sizes, int n_in,
                              void* d_out, int out_size, void* d_ws, size_t ws_size,
                              hipStream_t stream) {
    const float* z  = (const float*)d_in[0];
    const float* cb = (const float*)d_in[1];
    float* out = (float*)d_out;

    float*          loss_acc = (float*)d_ws;                    // @0
    unsigned*       counter  = (unsigned*)((char*)d_ws + 4);    // @4
    float*          norms    = (float*)((char*)d_ws + 256);     // 4 KB
    unsigned short* cbbf     = (unsigned short*)((char*)d_ws + 4608);  // 128 KB

    vq_prep<<<NCODES * 8 / 256, 256, 0, stream>>>(cb, norms, cbbf, loss_acc, counter);
    vq_main<<<GRID, BLOCK, 0, stream>>>(z, cb, norms, cbbf, out, loss_acc, counter);
}

// Round 5
// 112.784 us; speedup vs baseline: 5.8539x; 1.0720x over previous
//
#include <hip/hip_runtime.h>

// VectorQuantizer: z (32,64,64,64) fp32, codebook (1024,64) fp32.
// out = [z_q_st flat (8388608), vq_loss (1)]  (fp32)
// R5: full bf16 codebook in LDS; 512-thr blocks (8 waves), 4 A-tiles/wave;
// explicit depth-2 ping-pong prefetch of B fragments (the R4 stall was an
// unpipelined ds_read->MFMA->argmin chain); acc init hoisted (C=zero4),
// cinit = 1-|e|^2/2 precomputed + loaded as float4 per 4 jt; no atomics/fence
// (per-block partial -> plain store -> 64-thread finalize); epilogue reads
// bf16 codebook from LDS (no scattered global gather; adds <=2e-6 error).

constexpr int DIM    = 64;
constexpr int NCODES = 1024;
constexpr int HWSZ   = 4096;     // 64*64
constexpr int NPOS   = 131072;   // 32*4096
constexpr int BLOCK  = 512;      // 8 waves
constexpr int TPW    = 4;        // 16-row A-tiles per wave
constexpr int PPB    = 512;      // 8 waves * 64 rows
constexpr int GRID   = NPOS / PPB;   // 256 = 1 block/CU

typedef __bf16 bf16x8 __attribute__((ext_vector_type(8)));
typedef unsigned short ushort8t __attribute__((ext_vector_type(8)));
typedef float f32x4 __attribute__((ext_vector_type(4)));

__device__ __forceinline__ unsigned short f2bf(float f) {
    unsigned u = __float_as_uint(f);
    u += 0x7fffu + ((u >> 16) & 1u);   // RTNE
    return (unsigned short)(u >> 16);
}

// Prep: codebook -> bf16, pre-swizzled (16B group g of row j at slot g^(j&7))
// so a LINEAR global_load_lds lands conflict-free; cinitT[r][jt] = 1 - |e|^2/2
// transposed so a float4 covers 4 jt for lane r.
__global__ __launch_bounds__(256) void vq_prep(const float* __restrict__ cb,
                                               float* __restrict__ cinitT,
                                               unsigned short* __restrict__ cbbf) {
    int m = blockIdx.x * 256 + threadIdx.x;   // 0..8191: (row j, group g)
    int j = m >> 3, g = m & 7;
    const float4* src = (const float4*)(cb + (size_t)j * DIM + g * 8);
    float4 v0 = src[0], v1 = src[1];
    ushort8t u;
    u[0] = f2bf(v0.x); u[1] = f2bf(v0.y); u[2] = f2bf(v0.z); u[3] = f2bf(v0.w);
    u[4] = f2bf(v1.x); u[5] = f2bf(v1.y); u[6] = f2bf(v1.z); u[7] = f2bf(v1.w);
    float ps = v0.x * v0.x + v0.y * v0.y + v0.z * v0.z + v0.w * v0.w
             + v1.x * v1.x + v1.y * v1.y + v1.z * v1.z + v1.w * v1.w;
    ps += __shfl_xor(ps, 1, 64);
    ps += __shfl_xor(ps, 2, 64);
    ps += __shfl_xor(ps, 4, 64);
    if (g == 0) cinitT[(j & 15) * 64 + (j >> 4)] = fmaf(-0.5f, ps, 1.0f);
    *(ushort8t*)(cbbf + ((size_t)j * 8 + (g ^ (j & 7))) * 8) = u;
}

__global__ __launch_bounds__(BLOCK, 2) void vq_main(const float* __restrict__ z,
                                                    const float* __restrict__ cinitT,
                                                    const unsigned short* __restrict__ cbbf,
                                                    float* __restrict__ out,
                                                    float* __restrict__ wsblk) {
    __shared__ __align__(16) unsigned short cb_lds[NCODES * DIM];  // 128 KB
    __shared__ int   bj_lds[PPB];                                  // 2 KB
    __shared__ float ls_lds[BLOCK / 64];

    const int tid  = threadIdx.x;
    const int w    = tid >> 6;        // wave 0..7
    const int lane = tid & 63;
    const int q    = lane >> 4;       // quad 0..3
    const int r    = lane & 15;
    const int p0   = blockIdx.x * PPB;
    const int b    = p0 >> 12;
    const int hwb  = p0 & 4095;

    // ---- One-time staging of the whole bf16 codebook (128 KB, 16 DMA sweeps) ----
#pragma unroll
    for (int it = 0; it < (NCODES * DIM * 2) / (BLOCK * 16); it++) {
        int off = (it * BLOCK + tid) * 16;
        __builtin_amdgcn_global_load_lds(
            (const __attribute__((address_space(1))) void*)((const char*)cbbf + off),
            (__attribute__((address_space(3))) void*)((char*)cb_lds + off), 16, 0, 0);
    }

    // ---- A fragments: 4 n-tiles per wave (overlaps with staging DMA). ----
    // A layout (16x16x32): lane holds A[m=r][k=q*8+i] per K-half.
    bf16x8 afrag[TPW][2];
    float  zsq[TPW];
    const float* zb = z + (size_t)b * DIM * HWSZ + hwb + w * 64 + r;
#pragma unroll
    for (int t = 0; t < TPW; t++) {
        float sq = 0.f;
#pragma unroll
        for (int h = 0; h < 2; h++) {
            ushort8t u;
#pragma unroll
            for (int i = 0; i < 8; i++) {
                float v = zb[(size_t)(h * 32 + q * 8 + i) * HWSZ + t * 16];
                sq = fmaf(v, v, sq);
                u[i] = f2bf(v);
            }
            afrag[t][h] = __builtin_bit_cast(bf16x8, u);
        }
        sq += __shfl_xor(sq, 16, 64);   // sum quads -> full |z_row|^2
        sq += __shfl_xor(sq, 32, 64);
        zsq[t] = sq;
    }

    unsigned best[TPW][4];
#pragma unroll
    for (int t = 0; t < TPW; t++)
#pragma unroll
        for (int g = 0; g < 4; g++) best[t][g] = 0u;   // packed scores are > 0

    __syncthreads();   // staging complete; barrier-free until the loss reduce

    // ---- Software-pipelined sweep: ping-pong B buffers, depth-2 prefetch ----
    bf16x8 B[2][2];
    float4 ci[2];
#pragma unroll
    for (int s = 0; s < 2; s++) {        // initial B for jt=0,1
        int row = s * 16 + r;
#pragma unroll
        for (int h = 0; h < 2; h++) {
            int grp = (h * 4 + q) ^ (row & 7);
            B[s][h] = *(const bf16x8*)&cb_lds[(size_t)row * 64 + grp * 8];
        }
    }
    ci[0] = *(const float4*)(cinitT + r * 64 + 0);
    ci[1] = *(const float4*)(cinitT + r * 64 + 4);

    const f32x4 zero4 = {0.f, 0.f, 0.f, 0.f};

    for (int G2 = 0; G2 < 8; G2++) {
#pragma unroll
        for (int gg = 0; gg < 2; gg++) {           // group G = G2*2+gg (4 jt each)
#pragma unroll
            for (int e = 0; e < 4; e++) {
                const int jt   = G2 * 8 + gg * 4 + e;
                const int slot = e & 1;            // == jt&1 (compile-time)
                const int row  = jt * 16 + r;
                const float    cin   = ci[gg][e];
                const unsigned inv_j = (unsigned)(1023 - row);
#pragma unroll
                for (int t = 0; t < TPW; t++) {
                    f32x4 acc = __builtin_amdgcn_mfma_f32_16x16x32_bf16(
                        afrag[t][0], B[slot][0], zero4, 0, 0, 0);
                    acc = __builtin_amdgcn_mfma_f32_16x16x32_bf16(
                        afrag[t][1], B[slot][1], acc, 0, 0, 0);
#pragma unroll
                    for (int g = 0; g < 4; g++) {
                        // score = cin + dot > 0 -> monotone bits; low 10 bits = 1023-j
                        unsigned bits = (__float_as_uint(cin + acc[g]) & ~1023u) | inv_j;
                        best[t][g] = best[t][g] > bits ? best[t][g] : bits;
                    }
                }
                // refill this slot for jt+2 (wrap harmlessly at the tail)
                const int rown = ((jt + 2) & 63) * 16 + r;
#pragma unroll
                for (int h = 0; h < 2; h++) {
                    int grp = (h * 4 + q) ^ (rown & 7);
                    B[slot][h] = *(const bf16x8*)&cb_lds[(size_t)rown * 64 + grp * 8];
                }
            }
            ci[gg] = *(const float4*)(cinitT + r * 64 + ((G2 * 2 + gg + 2) & 15) * 4);
        }
    }

    // ---- Column-argmax reduce over the 16 j-lanes of each quad ----
#pragma unroll
    for (int t = 0; t < TPW; t++)
#pragma unroll
        for (int g = 0; g < 4; g++) {
            unsigned v = best[t][g];
#pragma unroll
            for (int off = 1; off < 16; off <<= 1) {
                unsigned v2 = __shfl_xor((int)v, off, 64);
                v = v > v2 ? v : v2;
            }
            best[t][g] = v;
        }

    // Writer lane for row m=r: quad q == r>>2 holds best for g == r&3.
    float lsum = 0.f;
    if (q == (r >> 2)) {
        int g = r & 3;
#pragma unroll
        for (int t = 0; t < TPW; t++) {
            unsigned v = best[t][0];
            v = (g == 1) ? best[t][1] : v;
            v = (g == 2) ? best[t][2] : v;
            v = (g == 3) ? best[t][3] : v;
            bj_lds[w * 64 + t * 16 + r] = 1023 - (int)(v & 1023u);
            // dist = |z|^2 + nj - 2*dot = zsq + 2 - 2*score  (low-bit err <= 2.4e-4)
            lsum += zsq[t] + 2.f - 2.f * __uint_as_float(v);
        }
    }
#pragma unroll
    for (int off = 32; off > 0; off >>= 1) lsum += __shfl_down(lsum, off, 64);
    if (lane == 0) ls_lds[w] = lsum;
    __syncthreads();
    if (tid == 0) {
        float s = 0.f;
#pragma unroll
        for (int i = 0; i < BLOCK / 64; i++) s += ls_lds[i];
        wsblk[blockIdx.x] = s;           // plain store; no fence, no atomics
    }

    // ---- Epilogue: bf16 codebook row from LDS (resident), scatter NCHW.
    // One position per thread; 64 consecutive positions per store instr. ----
    int myj = bj_lds[tid];
    int rc  = myj & 7;
    float* ob = out + (size_t)b * DIM * HWSZ + hwb + tid;
#pragma unroll
    for (int g = 0; g < 8; g++) {
        int gs = g ^ rc;                 // un-swizzle
        ushort8t u = *(const ushort8t*)&cb_lds[(size_t)myj * 64 + gs * 8];
#pragma unroll
        for (int i = 0; i < 8; i++) {
            ob[(size_t)(g * 8 + i) * HWSZ] = __uint_as_float(((unsigned)u[i]) << 16);
        }
    }
}

__global__ void vq_fin(const float* __restrict__ wsblk, float* __restrict__ out_loss) {
    int t = threadIdx.x;   // 64 threads, 1 wave
    float s = wsblk[t] + wsblk[t + 64] + wsblk[t + 128] + wsblk[t + 192];
#pragma unroll
    for (int off = 32; off > 0; off >>= 1) s += __shfl_down(s, off, 64);
    if (t == 0) out_loss[0] = 1.25f * s / (float)((size_t)NPOS * DIM);
}

extern "C" void kernel_launch(void* const* d_in, const int* in_sizes, int n_in,
                              void* d_out, int out_size, void* d_ws, size_t ws_size,
                              hipStream_t stream) {
    const float* z  = (const float*)d_in[0];
    const float* cb = (const float*)d_in[1];
    float* out = (float*)d_out;

    float*          cinitT = (float*)d_ws;                           // 4 KB
    unsigned short* cbbf   = (unsigned short*)((char*)d_ws + 4096);  // 128 KB
    float*          wsblk  = (float*)((char*)d_ws + 4096 + 131072);  // 1 KB

    vq_prep<<<NCODES * 8 / 256, 256, 0, stream>>>(cb, cinitT, cbbf);
    vq_main<<<GRID, BLOCK, 0, stream>>>(z, cinitT, cbbf, out, wsblk);
    vq_fin<<<1, 64, 0, stream>>>(wsblk, out + (size_t)NPOS * DIM);
}